// Round 2
// baseline (5280.415 us; speedup 1.0000x reference)
//
#include <hip/hip_runtime.h>

#define SEQ 256
#define BS 64
#define INF 512
#define HID 1024
#define KEXP 4
#define G4 4096          // 4*HID
#define NTOT 16384       // KEXP*G4

typedef __attribute__((ext_vector_type(8))) short s16x8;
typedef __attribute__((ext_vector_type(4))) float f32x4;

__device__ __forceinline__ short f2bf(float x) {
  unsigned u = __builtin_bit_cast(unsigned, x);
  u += 0x7fffu + ((u >> 16) & 1u);
  return (short)(u >> 16);
}

__device__ __forceinline__ float sigf(float x) {
  return 1.f / (1.f + __expf(-x));
}
__device__ __forceinline__ float tanhfast(float x) {
  return 2.f / (1.f + __expf(-2.f * x)) - 1.f;
}

__global__ void cvt_kernel(const float* __restrict__ s, short* __restrict__ d, int n4) {
  int stride = gridDim.x * blockDim.x;
  for (int i = blockIdx.x * blockDim.x + threadIdx.x; i < n4; i += stride) {
    float4 v = reinterpret_cast<const float4*>(s)[i];
    short4 o = make_short4(f2bf(v.x), f2bf(v.y), f2bf(v.z), f2bf(v.w));
    reinterpret_cast<short4*>(d)[i] = o;
  }
}

__global__ void prep_misc(const float* __restrict__ h0, const float* __restrict__ c0,
                          const float* __restrict__ coef, const float* __restrict__ bih,
                          const float* __restrict__ bhh, short* __restrict__ hbuf0,
                          float* __restrict__ cst, float* __restrict__ biasbuf,
                          float* __restrict__ wtsbuf) {
  int i = blockIdx.x * blockDim.x + threadIdx.x;   // 65536 threads == BS*HID
  cst[i] = c0[i];
  hbuf0[i] = f2bf(h0[i]);
  if (i < KEXP * G4) biasbuf[i] = bih[i] + bhh[i];
  if (i < SEQ) {
    float a = coef[i*4+0], b = coef[i*4+1], c = coef[i*4+2], d = coef[i*4+3];
    float m = fmaxf(fmaxf(a, b), fmaxf(c, d));
    float ea = __expf(a-m), eb = __expf(b-m), ec = __expf(c-m), ed = __expf(d-m);
    float inv = 1.f / (ea+eb+ec+ed);
    wtsbuf[i*4+0]=ea*inv; wtsbuf[i*4+1]=eb*inv; wtsbuf[i*4+2]=ec*inv; wtsbuf[i*4+3]=ed*inv;
  }
}

// One timestep. Grid: 256 WGs x 256 threads. WG wg owns h-cols [wg*4, wg*4+4)
// for ALL experts k and all 4 gates => 64 output cols x 64 batch rows.
// Wave w == expert k. C tile per wave: 64 rows(b) x 16 cols (4 gates x 4 j).
__global__ __launch_bounds__(256) void step_kernel(
    const short* __restrict__ Whh,   // [K][4096][1024] bf16 bits
    const short* __restrict__ Wih,   // [K][4096][512]
    const short* __restrict__ xb,    // [SEQ][64][512]
    const float* __restrict__ biasbuf, // [K][4096]
    const float* __restrict__ wtsbuf,  // [SEQ][K]
    const short* __restrict__ h_in,  // [64][1024] bf16
    short* __restrict__ h_out,       // [64][1024] bf16
    float* __restrict__ cst,         // [64][1024] f32
    float* __restrict__ outf,        // d_out base (f32)
    int t, int last)
{
  __shared__ short sA[16384];            // 2 bufs x [64 rows][128 k] bf16 (32KB)
  __shared__ float sG[KEXP * 64 * 17];   // gate pre-activations, padded (17KB)

  const int tid = threadIdx.x;
  const int w = tid >> 6;            // wave = expert k
  const int lane = tid & 63;
  const int wg = blockIdx.x;         // h-chunk: cols wg*4 .. wg*4+3
  const int n16 = lane & 15;         // col within wave tile
  const int gate = n16 >> 2, j = n16 & 3;
  const int wrow = w * G4 + gate * HID + wg * 4 + j;      // W row (output col)
  const short* whh_row = Whh + (size_t)wrow * 1024 + ((lane >> 4) * 8);
  const short* wih_row = Wih + (size_t)wrow * 512  + ((lane >> 4) * 8);

  f32x4 acc[4];
  #pragma unroll
  for (int m = 0; m < 4; ++m) acc[m] = (f32x4){0.f, 0.f, 0.f, 0.f};

  // stage chunk c (128 k-elems for all 64 rows) into buffer buf, XOR-swizzled.
  auto stage = [&](int buf, int c) {
    #pragma unroll
    for (int rr = 0; rr < 4; ++rr) {
      const int q = w * 1024 + lane * 16 + rr * 4096;   // byte offset in buffer
      const int row = q >> 8;                           // 0..63
      const int kb = (q & 255) ^ ((row & 7) << 4);      // logical byte-in-row
      const short* g;
      if (c < 8) g = h_in + row * 1024 + c * 128 + (kb >> 1);
      else       g = xb + (size_t)t * (BS * INF) + row * 512 + (c - 8) * 128 + (kb >> 1);
      short* l = sA + buf * 8192 + ((w * 1024 + rr * 4096) >> 1);  // wave-uniform base
      __builtin_amdgcn_global_load_lds((const __attribute__((address_space(1))) void*)g,
                                       (__attribute__((address_space(3))) void*)l,
                                       16, 0, 0);
    }
  };

  stage(0, 0);
  __syncthreads();

  for (int c = 0; c < 12; ++c) {
    if (c + 1 < 12) stage((c + 1) & 1, c + 1);
    const int buf = c & 1;
    #pragma unroll
    for (int kk = 0; kk < 4; ++kk) {
      const int kd = c * 128 + kk * 32;
      s16x8 bfrag;
      if (c < 8) bfrag = *reinterpret_cast<const s16x8*>(whh_row + kd);
      else       bfrag = *reinterpret_cast<const s16x8*>(wih_row + (kd - 1024));
      #pragma unroll
      for (int m = 0; m < 4; ++m) {
        const int row = m * 16 + (lane & 15);
        const int kbyte = kk * 64 + ((lane >> 4) * 16);
        const int addr = row * 256 + (kbyte ^ ((row & 7) << 4));   // bytes
        s16x8 afrag = *reinterpret_cast<const s16x8*>(sA + buf * 8192 + (addr >> 1));
        acc[m] = __builtin_amdgcn_mfma_f32_16x16x32_bf16(afrag, bfrag, acc[m], 0, 0, 0);
      }
    }
    __syncthreads();
  }

  // epilogue phase 1: spill accs to LDS. C/D layout: col=lane&15, row=(lane>>4)*4+reg
  #pragma unroll
  for (int m = 0; m < 4; ++m) {
    #pragma unroll
    for (int r = 0; r < 4; ++r) {
      const int b = m * 16 + ((lane >> 4) * 4) + r;
      sG[(w * 64 + b) * 17 + n16] = acc[m][r];
    }
  }
  __syncthreads();

  // epilogue phase 2: thread owns (b, jj)
  {
    const int b = tid >> 2, jj = tid & 3;
    const int hcol = wg * 4 + jj;
    const int hidx = b * HID + hcol;
    float cprev = cst[hidx];
    float hn = 0.f, cn = 0.f;
    #pragma unroll
    for (int k = 0; k < KEXP; ++k) {
      const float* sgb = &sG[(k * 64 + b) * 17];
      float iv = sgb[0 * 4 + jj] + biasbuf[k * G4 + 0 * HID + hcol];
      float fv = sgb[1 * 4 + jj] + biasbuf[k * G4 + 1 * HID + hcol];
      float gv = sgb[2 * 4 + jj] + biasbuf[k * G4 + 2 * HID + hcol];
      float ov = sgb[3 * 4 + jj] + biasbuf[k * G4 + 3 * HID + hcol];
      float is = sigf(iv), fs = sigf(fv), gs = tanhfast(gv), os = sigf(ov);
      float ck = fs * cprev + is * gs;
      float hk = os * tanhfast(ck);
      float wk = wtsbuf[t * 4 + k];
      hn += wk * hk;
      cn += wk * ck;
    }
    cst[hidx] = cn;
    h_out[hidx] = f2bf(hn);
    outf[(size_t)t * (BS * HID) + hidx] = hn;
    if (last) {
      outf[(size_t)SEQ * BS * HID + hidx] = hn;              // final h
      outf[(size_t)SEQ * BS * HID + BS * HID + hidx] = cn;   // final c
    }
  }
}

extern "C" void kernel_launch(void* const* d_in, const int* in_sizes, int n_in,
                              void* d_out, int out_size, void* d_ws, size_t ws_size,
                              hipStream_t stream) {
  const float* x    = (const float*)d_in[0];
  const float* h0   = (const float*)d_in[1];
  const float* c0   = (const float*)d_in[2];
  const float* coef = (const float*)d_in[3];
  const float* Wih  = (const float*)d_in[4];
  const float* Whh  = (const float*)d_in[5];
  const float* bih  = (const float*)d_in[6];
  const float* bhh  = (const float*)d_in[7];
  float* out = (float*)d_out;
  char* ws = (char*)d_ws;

  short* whh_b   = (short*)(ws);                    // 33554432 B
  short* wih_b   = (short*)(ws + 33554432);         // 16777216 B
  short* xb      = (short*)(ws + 50331648);         // 16777216 B
  float* biasbuf = (float*)(ws + 67108864);         // 65536 B
  float* wtsbuf  = (float*)(ws + 67174400);         // 4096 B
  short* hbuf    = (short*)(ws + 67178496);         // 2 x 131072 B
  float* cstate  = (float*)(ws + 67440640);         // 262144 B

  cvt_kernel<<<2048, 256, 0, stream>>>(Whh, whh_b, (KEXP * G4 * HID) / 4);
  cvt_kernel<<<2048, 256, 0, stream>>>(Wih, wih_b, (KEXP * G4 * INF) / 4);
  cvt_kernel<<<2048, 256, 0, stream>>>(x,   xb,    (SEQ * BS * INF) / 4);
  prep_misc<<<256, 256, 0, stream>>>(h0, c0, coef, bih, bhh,
                                     hbuf, cstate, biasbuf, wtsbuf);

  for (int t = 0; t < SEQ; ++t) {
    step_kernel<<<256, 256, 0, stream>>>(
        whh_b, wih_b, xb, biasbuf, wtsbuf,
        hbuf + (t & 1) * (BS * HID), hbuf + ((t + 1) & 1) * (BS * HID),
        cstate, out, t, (t == SEQ - 1) ? 1 : 0);
  }
}

// Round 3
// 4158.755 us; speedup vs baseline: 1.2697x; 1.2697x over previous
//
#include <hip/hip_runtime.h>

#define SEQ 256
#define BS 64
#define INF 512
#define HID 1024
#define KEXP 4
#define G4 4096          // 4*HID

typedef __attribute__((ext_vector_type(8))) short s16x8;
typedef __attribute__((ext_vector_type(4))) float f32x4;

__device__ __forceinline__ short f2bf(float x) {
  unsigned u = __builtin_bit_cast(unsigned, x);
  u += 0x7fffu + ((u >> 16) & 1u);
  return (short)(u >> 16);
}

__device__ __forceinline__ float sigf(float x) {
  return 1.f / (1.f + __expf(-x));
}
__device__ __forceinline__ float tanhfast(float x) {
  return 2.f / (1.f + __expf(-2.f * x)) - 1.f;
}

__global__ void cvt_kernel(const float* __restrict__ s, short* __restrict__ d, int n4) {
  int stride = gridDim.x * blockDim.x;
  for (int i = blockIdx.x * blockDim.x + threadIdx.x; i < n4; i += stride) {
    float4 v = reinterpret_cast<const float4*>(s)[i];
    short4 o = make_short4(f2bf(v.x), f2bf(v.y), f2bf(v.z), f2bf(v.w));
    reinterpret_cast<short4*>(d)[i] = o;
  }
}

// Convert W (f32) into bf16 MFMA B-fragment order:
// Wf[((k*256+wg)*48 + kk)*512 + lane*8 + e] =
//   W[k, gate*1024 + wg*4 + j, kk*32 + (lane>>4)*8 + e]
// where gate=(lane&15)>>2, j=lane&3; kk<32 -> Whh (cols 0..1023), else Wih.
// One thread per (frag, lane): reads 8 consecutive f32, writes 16B coalesced.
__global__ __launch_bounds__(256) void wf_cvt(const float* __restrict__ Whh,
                                              const float* __restrict__ Wih,
                                              short* __restrict__ Wf) {
  const int t = blockIdx.x * 256 + threadIdx.x;   // 3,145,728 threads
  const int lane = t & 63;
  const int f = t >> 6;                           // frag index, wave-uniform
  const int kk = f % 48;
  const int wgk = f / 48;
  const int wg = wgk & 255;
  const int k = wgk >> 8;
  const int row = k * G4 + ((lane & 15) >> 2) * HID + wg * 4 + (lane & 3);
  const int colbase = kk * 32 + ((lane >> 4) * 8);
  const float* src;
  if (kk < 32) src = Whh + (size_t)row * HID + colbase;
  else         src = Wih + (size_t)row * INF + (colbase - HID);
  float4 a = reinterpret_cast<const float4*>(src)[0];
  float4 b = reinterpret_cast<const float4*>(src)[1];
  s16x8 o;
  o[0]=f2bf(a.x); o[1]=f2bf(a.y); o[2]=f2bf(a.z); o[3]=f2bf(a.w);
  o[4]=f2bf(b.x); o[5]=f2bf(b.y); o[6]=f2bf(b.z); o[7]=f2bf(b.w);
  *reinterpret_cast<s16x8*>(Wf + (size_t)t * 8) = o;
}

__global__ void prep_misc(const float* __restrict__ h0, const float* __restrict__ c0,
                          const float* __restrict__ coef, const float* __restrict__ bih,
                          const float* __restrict__ bhh, short* __restrict__ hbuf0,
                          float* __restrict__ cst, float* __restrict__ biasbuf,
                          float* __restrict__ wtsbuf) {
  int i = blockIdx.x * blockDim.x + threadIdx.x;   // 65536 threads == BS*HID
  cst[i] = c0[i];
  hbuf0[i] = f2bf(h0[i]);
  if (i < KEXP * G4) biasbuf[i] = bih[i] + bhh[i];
  if (i < SEQ) {
    float a = coef[i*4+0], b = coef[i*4+1], c = coef[i*4+2], d = coef[i*4+3];
    float m = fmaxf(fmaxf(a, b), fmaxf(c, d));
    float ea = __expf(a-m), eb = __expf(b-m), ec = __expf(c-m), ed = __expf(d-m);
    float inv = 1.f / (ea+eb+ec+ed);
    wtsbuf[i*4+0]=ea*inv; wtsbuf[i*4+1]=eb*inv; wtsbuf[i*4+2]=ec*inv; wtsbuf[i*4+3]=ed*inv;
  }
}

// One timestep. Grid: 256 WGs x 512 threads (8 waves = 4 experts x 2 batch
// halves -> 2 waves/SIMD). WG wg owns h-cols [wg*4, wg*4+4) for all experts
// and gates. Wave w: expert k=w&3, batch half mh=w>>2 (rows mh*32..+32).
__global__ __launch_bounds__(512) void step_kernel(
    const short* __restrict__ Wf,    // fragment-ordered weights (bf16 bits)
    const short* __restrict__ xb,    // [SEQ][64][512] bf16
    const float* __restrict__ biasbuf, // [K][4096]
    const float* __restrict__ wtsbuf,  // [SEQ][K]
    const short* __restrict__ h_in,  // [64][1024] bf16
    short* __restrict__ h_out,       // [64][1024] bf16
    float* __restrict__ cst,         // [64][1024] f32
    float* __restrict__ outf,        // d_out base (f32)
    int t, int last)
{
  __shared__ short sA[16384];            // 2 bufs x [64 rows][128 k] bf16 (32KB)
  __shared__ float sG[KEXP * 64 * 17];   // gate pre-activations, padded (17KB)

  const int tid = threadIdx.x;
  const int w = tid >> 6;            // wave id 0..7
  const int lane = tid & 63;
  const int k = w & 3;               // expert
  const int mh = w >> 2;             // batch half
  const int wg = blockIdx.x;         // h-chunk: cols wg*4 .. wg*4+3
  const int n16 = lane & 15;

  // coalesced B: frag base for (k, wg); frag kk at + kk*512 shorts
  const short* wfb = Wf + ((size_t)(k * 256 + wg) * 48) * 512 + lane * 8;

  f32x4 acc[2];
  acc[0] = (f32x4){0.f, 0.f, 0.f, 0.f};
  acc[1] = (f32x4){0.f, 0.f, 0.f, 0.f};

  // stage chunk c (128 k-elems for all 64 rows) into buffer buf, XOR-swizzled
  // (linear LDS dest + pre-swizzled global source; read applies same XOR).
  auto stage = [&](int buf, int c) {
    #pragma unroll
    for (int rr = 0; rr < 2; ++rr) {
      const int q = w * 1024 + lane * 16 + rr * 8192;   // byte offset in buffer
      const int row = q >> 8;                           // 0..63
      const int kb = (q & 255) ^ ((row & 7) << 4);      // logical byte-in-row
      const short* g;
      if (c < 8) g = h_in + row * 1024 + c * 128 + (kb >> 1);
      else       g = xb + (size_t)t * (BS * INF) + row * 512 + (c - 8) * 128 + (kb >> 1);
      short* l = sA + buf * 8192 + ((w * 1024 + rr * 8192) >> 1);  // wave-uniform base
      __builtin_amdgcn_global_load_lds((const __attribute__((address_space(1))) void*)g,
                                       (__attribute__((address_space(3))) void*)l,
                                       16, 0, 0);
    }
  };

  stage(0, 0);
  __syncthreads();

  for (int c = 0; c < 12; ++c) {
    if (c + 1 < 12) stage((c + 1) & 1, c + 1);
    const int buf = c & 1;
    #pragma unroll
    for (int kkk = 0; kkk < 4; ++kkk) {
      s16x8 bfrag = *reinterpret_cast<const s16x8*>(wfb + (c * 4 + kkk) * 512);
      #pragma unroll
      for (int m = 0; m < 2; ++m) {
        const int row = mh * 32 + m * 16 + n16;
        const int kbyte = kkk * 64 + ((lane >> 4) * 16);
        const int addr = row * 256 + (kbyte ^ ((row & 7) << 4));   // bytes
        s16x8 afrag = *reinterpret_cast<const s16x8*>(sA + buf * 8192 + (addr >> 1));
        acc[m] = __builtin_amdgcn_mfma_f32_16x16x32_bf16(afrag, bfrag, acc[m], 0, 0, 0);
      }
    }
    __syncthreads();
  }

  // epilogue phase 1: spill accs. C/D layout: col=lane&15, row=(lane>>4)*4+reg
  #pragma unroll
  for (int m = 0; m < 2; ++m) {
    #pragma unroll
    for (int r = 0; r < 4; ++r) {
      const int b = mh * 32 + m * 16 + ((lane >> 4) * 4) + r;
      sG[(k * 64 + b) * 17 + n16] = acc[m][r];
    }
  }
  __syncthreads();

  // epilogue phase 2: thread owns (b, jj)
  if (tid < 256) {
    const int b = tid >> 2, jj = tid & 3;
    const int hcol = wg * 4 + jj;
    const int hidx = b * HID + hcol;
    float cprev = cst[hidx];
    float hn = 0.f, cn = 0.f;
    #pragma unroll
    for (int kx = 0; kx < KEXP; ++kx) {
      const float* sgb = &sG[(kx * 64 + b) * 17];
      float iv = sgb[0 * 4 + jj] + biasbuf[kx * G4 + 0 * HID + hcol];
      float fv = sgb[1 * 4 + jj] + biasbuf[kx * G4 + 1 * HID + hcol];
      float gv = sgb[2 * 4 + jj] + biasbuf[kx * G4 + 2 * HID + hcol];
      float ov = sgb[3 * 4 + jj] + biasbuf[kx * G4 + 3 * HID + hcol];
      float is = sigf(iv), fs = sigf(fv), gs = tanhfast(gv), os = sigf(ov);
      float ck = fs * cprev + is * gs;
      float hk = os * tanhfast(ck);
      float wk = wtsbuf[t * 4 + kx];
      hn += wk * hk;
      cn += wk * ck;
    }
    cst[hidx] = cn;
    h_out[hidx] = f2bf(hn);
    outf[(size_t)t * (BS * HID) + hidx] = hn;
    if (last) {
      outf[(size_t)SEQ * BS * HID + hidx] = hn;              // final h
      outf[(size_t)SEQ * BS * HID + BS * HID + hidx] = cn;   // final c
    }
  }
}

extern "C" void kernel_launch(void* const* d_in, const int* in_sizes, int n_in,
                              void* d_out, int out_size, void* d_ws, size_t ws_size,
                              hipStream_t stream) {
  const float* x    = (const float*)d_in[0];
  const float* h0   = (const float*)d_in[1];
  const float* c0   = (const float*)d_in[2];
  const float* coef = (const float*)d_in[3];
  const float* Wih  = (const float*)d_in[4];
  const float* Whh  = (const float*)d_in[5];
  const float* bih  = (const float*)d_in[6];
  const float* bhh  = (const float*)d_in[7];
  float* out = (float*)d_out;
  char* ws = (char*)d_ws;

  short* wf      = (short*)(ws);                    // 50331648 B (48 MB)
  short* xb      = (short*)(ws + 50331648);         // 16777216 B
  float* biasbuf = (float*)(ws + 67108864);         // 65536 B
  float* wtsbuf  = (float*)(ws + 67174400);         // 4096 B
  short* hbuf    = (short*)(ws + 67178496);         // 2 x 131072 B
  float* cstate  = (float*)(ws + 67440640);         // 262144 B

  wf_cvt<<<12288, 256, 0, stream>>>(Whh, Wih, wf);
  cvt_kernel<<<2048, 256, 0, stream>>>(x, xb, (SEQ * BS * INF) / 4);
  prep_misc<<<256, 256, 0, stream>>>(h0, c0, coef, bih, bhh,
                                     hbuf, cstate, biasbuf, wtsbuf);

  for (int t = 0; t < SEQ; ++t) {
    step_kernel<<<256, 512, 0, stream>>>(
        wf, xb, biasbuf, wtsbuf,
        hbuf + (t & 1) * (BS * HID), hbuf + ((t + 1) & 1) * (BS * HID),
        cstate, out, t, (t == SEQ - 1) ? 1 : 0);
  }
}